// Round 7
// baseline (720.379 us; speedup 1.0000x reference)
//
#include <hip/hip_runtime.h>

// Attention (B=4, T=2048, dim=2048, H=16, hd=128) on gfx950.
// Pipeline: cast->bf16 | cos/sin table | fused QKV gemm (RoPE in epilogue) |
//           flash attention | out gemm.
// R9: fix R8's half-copied epilogues (Q/K and V restage read loops covered 1024 of
//     2048 16B units -> rows 64..127 never written; j<4 -> j<8). All else = R8:
//     m97-class 128x128 GEMMs (4 waves, BK=64, single 32KB LDS, ~3 blocks/CU),
//     RoPE fused in Q/K epilogue, flash = R5-verified form.
// Workspace layout (192 MiB):
//   xb[2^24] wqb wkb wvb wob[2^22 each] qb[2^24] kb[2^24] vtb[2^24] ab[2^24]  (bf16)
//   cs-table (1 MiB float2[2048][64]) aliases ab (dead until flash writes it).

using floatx4  = __attribute__((ext_vector_type(4))) float;
using short8   = __attribute__((ext_vector_type(8))) short;
using ushortx4 = __attribute__((ext_vector_type(4))) unsigned short;

#define DEVFN static __device__ __forceinline__

DEVFN unsigned short f2bf(float f) {          // RNE float->bf16
  unsigned u = __builtin_bit_cast(unsigned, f);
  u += 0x7fffu + ((u >> 16) & 1u);
  return (unsigned short)(u >> 16);
}
DEVFN float bf2f(unsigned short h) {
  return __builtin_bit_cast(float, ((unsigned)h) << 16);
}

DEVFN void async_cp16(const unsigned short* g, unsigned short* l) {
  __builtin_amdgcn_global_load_lds(
      (const __attribute__((address_space(1))) void*)g,
      (__attribute__((address_space(3))) void*)l,
      16, 0, 0);
}

// ---------------- cast fp32 -> bf16 (vectorized) ----------------
__global__ __launch_bounds__(256) void cast_kernel(const float4* __restrict__ in,
                                                   ushortx4* __restrict__ out) {
  long u = (long)blockIdx.x * 256 + threadIdx.x;
  float4 v = in[u];
  out[u] = (ushortx4){f2bf(v.x), f2bf(v.y), f2bf(v.z), f2bf(v.w)};
}

// ---------------- cos/sin table: cst[t][j] = {cos,sin}(pos[t]*freq_j) ----------------
__global__ __launch_bounds__(256) void cs_table_kernel(const float* __restrict__ pos,
                                                       float2* __restrict__ cst) {
  int idx = blockIdx.x * 256 + threadIdx.x;   // 2048*64 entries, grid 512
  int t = idx >> 6, j = idx & 63;
  float ang = pos[t] * exp2f(-0.20762051f * (float)j);  // 10000^(-j/64)
  cst[idx] = make_float2(cosf(ang), sinf(ang));
}

// ---------------- fused QKV GEMM (m97-class): C = A*W^T + bias -----------------
// M=8192 N=2048 K=2048, 3 weight matrices, one 3072-block launch (g = bid>>10).
// 128x128 tile, BK=64, 4 waves (2x2 of 64x64), 256 thr, single 32KB LDS buffer,
// drain vmcnt(0) per K-step; ~3 blocks/CU give inter-block stage/compute overlap.
// LDS swizzle: row = one 128B line; phys_chunk = chunk ^ (row&7) (8x16B chunks/row);
// stage = linear LDS dst + inverse-swizzled global src (both-sides, rule 21).
// Epilogue per g: g<2 -> bf16 [B,H,T,hd] with RoPE (n-tile = 1 head);
//                 g==2 -> bf16 [B,H,hd,T] (V transposed). LDS-restaged 16B stores.
__global__ __launch_bounds__(256) void qkv_gemm(
    const unsigned short* __restrict__ A,
    const unsigned short* __restrict__ Wq, const unsigned short* __restrict__ Wk,
    const unsigned short* __restrict__ Wv,
    const float* __restrict__ bq, const float* __restrict__ bk,
    const float* __restrict__ bv,
    unsigned short* __restrict__ Oq, unsigned short* __restrict__ Ok,
    unsigned short* __restrict__ Ov,
    const float2* __restrict__ cst) {
  constexpr int K = 2048;
  constexpr int NT = 32;                         // K-steps of 64
  __shared__ __align__(16) unsigned short lds[16384];  // 32 KiB: A[0,8192) B[8192,16384)
  const int tid = threadIdx.x;
  const int wave = tid >> 6, lane = tid & 63;
  const int ln15 = lane & 15, quad = lane >> 4;
  const int wr = wave >> 1, wc = wave & 1;
  const int bid = blockIdx.x;
  const int g = bid >> 10;                       // 0:q 1:k 2:v
  const int b2 = bid & 1023;
  const unsigned short* Bw = (g == 0) ? Wq : (g == 1) ? Wk : Wv;
  const float* bias = (g == 0) ? bq : (g == 1) ? bk : bv;
  unsigned short* Cout = (g == 0) ? Oq : (g == 1) ? Ok : Ov;
  const int xcd = b2 & 7, s = b2 >> 3;           // s in [0,128)
  const int m0 = (xcd * 8 + (s & 7)) * 128;      // 8 m-tiles per XCD (A L2-resident)
  const int n0 = (s >> 3) * 128;                 // 16 n-tiles (one head each)

  // stage sources: unit u -> row L=u>>3, phys p=u&7, logical chunk c=p^(L&7)
  const unsigned short *sA0, *sA1, *sA2, *sA3, *sB0, *sB1, *sB2, *sB3;
#define MKSRC(j, pa, pb)                                                \
  {                                                                     \
    int u = (j) * 256 + tid;                                            \
    int L = u >> 3, c = (u & 7) ^ (L & 7);                              \
    pa = A + (long)(m0 + L) * K + c * 8;                                \
    pb = Bw + (long)(n0 + L) * K + c * 8;                               \
  }
  MKSRC(0, sA0, sB0) MKSRC(1, sA1, sB1) MKSRC(2, sA2, sB2) MKSRC(3, sA3, sB3)
#undef MKSRC

  // read rows (loop-invariant); k-chunk per ks: phys = (ks*4+quad) ^ (row&7)
  int rowA[4], rowB[4];
#pragma unroll
  for (int i = 0; i < 4; ++i) {
    rowA[i] = wr * 64 + i * 16 + ln15;
    rowB[i] = wc * 64 + i * 16 + ln15;
  }

  floatx4 acc[4][4];
#pragma unroll
  for (int i = 0; i < 4; ++i)
#pragma unroll
    for (int j = 0; j < 4; ++j) acc[i][j] = (floatx4){0.f, 0.f, 0.f, 0.f};

  for (int t = 0; t < NT; ++t) {
    __syncthreads();                             // everyone done reading prev tile
#pragma unroll
    for (int j = 0; j < 4; ++j) {
      const unsigned short* pa = (j == 0) ? sA0 : (j == 1) ? sA1 : (j == 2) ? sA2 : sA3;
      const unsigned short* pb = (j == 0) ? sB0 : (j == 1) ? sB1 : (j == 2) ? sB2 : sB3;
      async_cp16(pa + (long)t * 64, lds + (j * 256 + wave * 64) * 8);
      async_cp16(pb + (long)t * 64, lds + 8192 + (j * 256 + wave * 64) * 8);
    }
    asm volatile("s_waitcnt vmcnt(0)" ::: "memory");
    __syncthreads();
#pragma unroll
    for (int ks = 0; ks < 2; ++ks) {
      short8 af[4], bf4[4];
#pragma unroll
      for (int mi = 0; mi < 4; ++mi) {
        int phys = (ks * 4 + quad) ^ (rowA[mi] & 7);
        af[mi] = *(const short8*)(lds + rowA[mi] * 64 + phys * 8);
      }
#pragma unroll
      for (int nj = 0; nj < 4; ++nj) {
        int phys = (ks * 4 + quad) ^ (rowB[nj] & 7);
        bf4[nj] = *(const short8*)(lds + 8192 + rowB[nj] * 64 + phys * 8);
      }
      __builtin_amdgcn_s_setprio(1);
#pragma unroll
      for (int mi = 0; mi < 4; ++mi)
#pragma unroll
        for (int nj = 0; nj < 4; ++nj)
          acc[mi][nj] = __builtin_amdgcn_mfma_f32_16x16x32_bf16(af[mi], bf4[nj],
                                                                acc[mi][nj], 0, 0, 0);
      __builtin_amdgcn_s_setprio(0);
    }
  }
  __syncthreads();                               // protect LDS before epilogue reuse

  const int b_ = m0 >> 11;
  const int t0m = m0 & 2047;
  const int h = n0 >> 7;                         // exactly one head per n-tile

  if (g == 2) {
    // V: out [b][h][d][t]. LDS [128 d][128 t] bf16, chunk c=t>>3 (16), phys=c^(d&15)
#pragma unroll
    for (int nj = 0; nj < 4; ++nj) {
      int nloc = wc * 64 + nj * 16 + ln15;       // d
      float bv = bias[n0 + nloc];
#pragma unroll
      for (int mi = 0; mi < 4; ++mi)
#pragma unroll
        for (int r = 0; r < 4; ++r) {
          int tl = wr * 64 + mi * 16 + quad * 4 + r;
          int phys = (tl >> 3) ^ (nloc & 15);
          lds[nloc * 128 + phys * 8 + (tl & 7)] = f2bf(acc[mi][nj][r] + bv);
        }
    }
    __syncthreads();
#pragma unroll
    for (int j = 0; j < 8; ++j) {                // 2048 16B units / 256 threads
      int u = j * 256 + tid;
      int d = u >> 4, c = u & 15;
      int phys = c ^ (d & 15);
      *(short8*)(Cout + ((((long)(b_ * 16 + h)) << 7) + d) * 2048 + t0m + c * 8) =
          *(const short8*)(lds + d * 128 + phys * 8);
    }
  } else {
    // Q/K: out [b][h][t][d] + RoPE. LDS [128 t][128 d] bf16, chunk c=d>>3, phys=c^(t&15)
#pragma unroll
    for (int nj = 0; nj < 4; ++nj) {
      int nloc = wc * 64 + nj * 16 + ln15;       // d
      float bv = bias[n0 + nloc];
#pragma unroll
      for (int mi = 0; mi < 4; ++mi)
#pragma unroll
        for (int r = 0; r < 4; ++r) {
          int tl = wr * 64 + mi * 16 + quad * 4 + r;
          int phys = (nloc >> 3) ^ (tl & 15);
          lds[tl * 128 + phys * 8 + (nloc & 7)] = f2bf(acc[mi][nj][r] + bv);
        }
    }
    __syncthreads();
#pragma unroll
    for (int j = 0; j < 8; ++j) {                // 2048 16B units / 256 threads
      int u = j * 256 + tid;
      int tl = u >> 4, c = u & 15;               // chunk c: d = c*8..c*8+8
      int phys = c ^ (tl & 15);
      int physp = (c ^ 8) ^ (tl & 15);           // partner chunk (d +/- 64)
      short8 s8 = *(const short8*)(lds + tl * 128 + phys * 8);
      short8 p8 = *(const short8*)(lds + tl * 128 + physp * 8);
      int tt = t0m + tl;
      const float2* ct = cst + tt * 64 + (c & 7) * 8;
      short8 o8;
#pragma unroll
      for (int e = 0; e < 8; ++e) {
        float2 cs = ct[e];
        float x = bf2f((unsigned short)s8[e]);
        float y = bf2f((unsigned short)p8[e]);
        float v = (c < 8) ? (x * cs.x - y * cs.y) : (x * cs.x + y * cs.y);
        o8[e] = (short)f2bf(v);
      }
      *(short8*)(Cout + ((((long)(b_ * 16 + h)) << 11) + tt) * 128 + c * 8) = o8;
    }
  }
}

// ---------------- output GEMM (wo, m97-class): fp32 out [M,N] ----------------
__global__ __launch_bounds__(256) void gemm_wo(const unsigned short* __restrict__ A,
                                               const unsigned short* __restrict__ Bw,
                                               const float* __restrict__ bias,
                                               float* __restrict__ Cout) {
  constexpr int K = 2048;
  constexpr int NT = 32;
  __shared__ __align__(16) unsigned short lds[16384];
  const int tid = threadIdx.x;
  const int wave = tid >> 6, lane = tid & 63;
  const int ln15 = lane & 15, quad = lane >> 4;
  const int wr = wave >> 1, wc = wave & 1;
  const int bid = blockIdx.x;
  const int xcd = bid & 7, s = bid >> 3;
  const int m0 = (xcd * 8 + (s & 7)) * 128;
  const int n0 = (s >> 3) * 128;

  const unsigned short *sA0, *sA1, *sA2, *sA3, *sB0, *sB1, *sB2, *sB3;
#define MKSRC(j, pa, pb)                                                \
  {                                                                     \
    int u = (j) * 256 + tid;                                            \
    int L = u >> 3, c = (u & 7) ^ (L & 7);                              \
    pa = A + (long)(m0 + L) * K + c * 8;                                \
    pb = Bw + (long)(n0 + L) * K + c * 8;                               \
  }
  MKSRC(0, sA0, sB0) MKSRC(1, sA1, sB1) MKSRC(2, sA2, sB2) MKSRC(3, sA3, sB3)
#undef MKSRC

  int rowA[4], rowB[4];
#pragma unroll
  for (int i = 0; i < 4; ++i) {
    rowA[i] = wr * 64 + i * 16 + ln15;
    rowB[i] = wc * 64 + i * 16 + ln15;
  }

  floatx4 acc[4][4];
#pragma unroll
  for (int i = 0; i < 4; ++i)
#pragma unroll
    for (int j = 0; j < 4; ++j) acc[i][j] = (floatx4){0.f, 0.f, 0.f, 0.f};

  for (int t = 0; t < NT; ++t) {
    __syncthreads();
#pragma unroll
    for (int j = 0; j < 4; ++j) {
      const unsigned short* pa = (j == 0) ? sA0 : (j == 1) ? sA1 : (j == 2) ? sA2 : sA3;
      const unsigned short* pb = (j == 0) ? sB0 : (j == 1) ? sB1 : (j == 2) ? sB2 : sB3;
      async_cp16(pa + (long)t * 64, lds + (j * 256 + wave * 64) * 8);
      async_cp16(pb + (long)t * 64, lds + 8192 + (j * 256 + wave * 64) * 8);
    }
    asm volatile("s_waitcnt vmcnt(0)" ::: "memory");
    __syncthreads();
#pragma unroll
    for (int ks = 0; ks < 2; ++ks) {
      short8 af[4], bf4[4];
#pragma unroll
      for (int mi = 0; mi < 4; ++mi) {
        int phys = (ks * 4 + quad) ^ (rowA[mi] & 7);
        af[mi] = *(const short8*)(lds + rowA[mi] * 64 + phys * 8);
      }
#pragma unroll
      for (int nj = 0; nj < 4; ++nj) {
        int phys = (ks * 4 + quad) ^ (rowB[nj] & 7);
        bf4[nj] = *(const short8*)(lds + 8192 + rowB[nj] * 64 + phys * 8);
      }
      __builtin_amdgcn_s_setprio(1);
#pragma unroll
      for (int mi = 0; mi < 4; ++mi)
#pragma unroll
        for (int nj = 0; nj < 4; ++nj)
          acc[mi][nj] = __builtin_amdgcn_mfma_f32_16x16x32_bf16(af[mi], bf4[nj],
                                                                acc[mi][nj], 0, 0, 0);
      __builtin_amdgcn_s_setprio(0);
    }
  }

  // fp32 epilogue: 2 rounds of 64 rows; LDS f32 [64][128], chunk c=n>>2, phys=c^(tl&15)
  float* lf = (float*)lds;
#pragma unroll
  for (int rnd = 0; rnd < 2; ++rnd) {
    __syncthreads();
    if (wr == rnd) {
#pragma unroll
      for (int nj = 0; nj < 4; ++nj) {
        int nloc = wc * 64 + nj * 16 + ln15;
        float bv = bias[n0 + nloc];
#pragma unroll
        for (int mi = 0; mi < 4; ++mi)
#pragma unroll
          for (int r = 0; r < 4; ++r) {
            int tl = mi * 16 + quad * 4 + r;
            int phys = (nloc >> 2) ^ (tl & 15);
            lf[tl * 128 + phys * 4 + (nloc & 3)] = acc[mi][nj][r] + bv;
          }
      }
    }
    __syncthreads();
#pragma unroll
    for (int j = 0; j < 8; ++j) {               // 2048 16B units / 256 threads
      int u = j * 256 + tid;
      int tl = u >> 5, c = u & 31;
      int phys = c ^ (tl & 15);
      int m = m0 + rnd * 64 + tl;
      *(floatx4*)(Cout + (long)m * 2048 + n0 + c * 4) =
          *(const floatx4*)(lf + tl * 128 + phys * 4);
    }
  }
}

// ---------------- flash attention (R5-verified softmax; R7 pipeline) ----------------
// Grid 512, 512 threads (8 waves x 32 q-rows). KVBLK=64, K/V gload_lds double-buffered,
// wave-private P, LDS-staged coalesced output.
__global__ __launch_bounds__(512, 2) void flash_kernel(
    const unsigned short* __restrict__ Q,    // [64][2048][128]
    const unsigned short* __restrict__ Kmat, // [64][2048][128]
    const unsigned short* __restrict__ Vt,   // [64][128][2048]
    unsigned short* __restrict__ Out) {      // [4][2048][2048]
  constexpr int T = 2048;
  constexpr float SCALE = 0.08838834764831845f;  // 1/sqrt(128)
  __shared__ __align__(16) unsigned short lds[49152];  // 96 KiB

  const int tid = threadIdx.x;
  const int wave = tid >> 6, lane = tid & 63;
  const int ln15 = lane & 15, quad = lane >> 4;
  const int l7 = ln15 & 7;
  const int bid = blockIdx.x;
  const int xcd = bid & 7, sl = bid >> 3;
  const int bh = xcd * 8 + (sl >> 3);
  const int q0 = (sl & 7) * 256;

  const unsigned short* Qb = Q + (long)bh * T * 128;
  const unsigned short* Kb = Kmat + (long)bh * T * 128;
  const unsigned short* Vb = Vt + (long)bh * 128 * T;
  unsigned short* pw = lds + 32768 + wave * 2048;

  short8 qf[2][4];
#pragma unroll
  for (int mi = 0; mi < 2; ++mi)
#pragma unroll
    for (int ks = 0; ks < 4; ++ks)
      qf[mi][ks] = *(const short8*)(Qb + (long)(q0 + wave * 32 + mi * 16 + ln15) * 128 +
                                    ks * 32 + quad * 8);

#define STAGE_KV(t, kdst, vdst)                                                  \
  do {                                                                           \
    _Pragma("unroll") for (int j = 0; j < 2; ++j) {                              \
      int u = j * 512 + tid;                                                     \
      int row = u >> 4;                                                          \
      int c = (u & 15) ^ (row & 15);                                             \
      async_cp16(Kb + (long)((t) * 64 + row) * 128 + c * 8,                      \
                 (kdst) + (j * 512 + wave * 64) * 8);                            \
    }                                                                            \
    _Pragma("unroll") for (int j = 0; j < 2; ++j) {                              \
      int u = j * 512 + tid;                                                     \
      int row = u >> 3;                                                          \
      int c = (u & 7) ^ (row & 7);                                               \
      async_cp16(Vb + (long)row * T + (t) * 64 + c * 8,                          \
                 (vdst) + (j * 512 + wave * 64) * 8);                            \
    }                                                                            \
  } while (0)

  STAGE_KV(0, lds, lds + 16384);
  asm volatile("s_waitcnt vmcnt(0)" ::: "memory");
  __syncthreads();

  floatx4 oacc[2][8];
#pragma unroll
  for (int mi = 0; mi < 2; ++mi)
#pragma unroll
    for (int nj = 0; nj < 8; ++nj) oacc[mi][nj] = (floatx4){0.f, 0.f, 0.f, 0.f};
  float mst[2][4], lsp[2][4];
#pragma unroll
  for (int mi = 0; mi < 2; ++mi)
#pragma unroll
    for (int r = 0; r < 4; ++r) { mst[mi][r] = -1e30f; lsp[mi][r] = 0.f; }

  for (int t = 0; t < 32; ++t) {
    unsigned short* kc = lds + (t & 1) * 8192;
    unsigned short* vc = lds + 16384 + (t & 1) * 8192;
    if (t < 31) {
      unsigned short* kn = lds + ((t + 1) & 1) * 8192;
      unsigned short* vn = lds + 16384 + ((t + 1) & 1) * 8192;
      STAGE_KV(t + 1, kn, vn);
    }

    floatx4 sacc[2][4];
#pragma unroll
    for (int mi = 0; mi < 2; ++mi)
#pragma unroll
      for (int ni = 0; ni < 4; ++ni) sacc[mi][ni] = (floatx4){0.f, 0.f, 0.f, 0.f};
#pragma unroll
    for (int ks = 0; ks < 4; ++ks) {
      short8 bfr[4];
#pragma unroll
      for (int ni = 0; ni < 4; ++ni) {
        int row = ni * 16 + ln15;
        int phys = (ks * 4 + quad) ^ ln15;
        bfr[ni] = *(const short8*)(kc + row * 128 + phys * 8);
      }
      __builtin_amdgcn_s_setprio(1);
#pragma unroll
      for (int mi = 0; mi < 2; ++mi)
#pragma unroll
        for (int ni = 0; ni < 4; ++ni)
          sacc[mi][ni] = __builtin_amdgcn_mfma_f32_16x16x32_bf16(qf[mi][ks], bfr[ni],
                                                                 sacc[mi][ni], 0, 0, 0);
      __builtin_amdgcn_s_setprio(0);
    }

    // online softmax (R5 form, unconditional rescale)
#pragma unroll
    for (int mi = 0; mi < 2; ++mi)
#pragma unroll
      for (int r = 0; r < 4; ++r) {
        float mx = fmaxf(fmaxf(sacc[mi][0][r], sacc[mi][1][r]),
                         fmaxf(sacc[mi][2][r], sacc[mi][3][r]));
#pragma unroll
        for (int off = 1; off < 16; off <<= 1) mx = fmaxf(mx, __shfl_xor(mx, off, 16));
        mx *= SCALE;
        float mold = mst[mi][r];
        float mnew = fmaxf(mold, mx);
        float alpha = __expf(mold - mnew);
        float rs = 0.f;
#pragma unroll
        for (int ni = 0; ni < 4; ++ni) {
          float p = __expf(sacc[mi][ni][r] * SCALE - mnew);
          sacc[mi][ni][r] = p;
          rs += p;
        }
        mst[mi][r] = mnew;
        lsp[mi][r] = lsp[mi][r] * alpha + rs;
#pragma unroll
        for (int nj = 0; nj < 8; ++nj) oacc[mi][nj][r] *= alpha;
      }

#pragma unroll
    for (int mi = 0; mi < 2; ++mi)
#pragma unroll
      for (int ni = 0; ni < 4; ++ni) {
        int cc = ni * 2 + (ln15 >> 3);
#pragma unroll
        for (int r = 0; r < 4; ++r) {
          int m = mi * 16 + quad * 4 + r;
          pw[m * 64 + (cc ^ (m & 7)) * 8 + l7] = f2bf(sacc[mi][ni][r]);
        }
      }

#pragma unroll
    for (int ks = 0; ks < 2; ++ks) {
      short8 af[2], bv[8];
#pragma unroll
      for (int mi = 0; mi < 2; ++mi) {
        int phys = (ks * 4 + quad) ^ l7;
        af[mi] = *(const short8*)(pw + (mi * 16 + ln15) * 64 + phys * 8);
      }
#pragma unroll
      for (int nj = 0; nj < 8; ++nj) {
        int row = nj * 16 + ln15;
        int phys = (ks * 4 + quad) ^ (row & 7);
        bv[nj] = *(const short8*)(vc + row * 64 + phys * 8);
      }
      __builtin_amdgcn_s_setprio(1);
#pragma unroll
      for (int mi = 0; mi < 2; ++mi)
#pragma unroll
        for (int nj = 0; nj < 8; ++nj)
          oacc[mi][nj] = __builtin_amdgcn_mfma_f32_16x16x32_bf16(af[mi], bv[nj],
                                                                 oacc[mi][nj], 0, 0, 0);
      __builtin_amdgcn_s_setprio(0);
    }

    asm volatile("s_waitcnt vmcnt(0)" ::: "memory");
    __syncthreads();
  }
#undef STAGE_KV

  float rinv[2][4];
#pragma unroll
  for (int mi = 0; mi < 2; ++mi)
#pragma unroll
    for (int r = 0; r < 4; ++r) {
      float l = lsp[mi][r];
#pragma unroll
      for (int off = 1; off < 16; off <<= 1) l += __shfl_xor(l, off, 16);
      rinv[mi][r] = 1.f / l;
    }
#pragma unroll
  for (int mi = 0; mi < 2; ++mi)
#pragma unroll
    for (int nj = 0; nj < 8; ++nj)
#pragma unroll
      for (int r = 0; r < 4; ++r)
        lds[(wave * 32 + mi * 16 + quad * 4 + r) * 128 + nj * 16 + ln15] =
            f2bf(oacc[mi][nj][r] * rinv[mi][r]);
  __syncthreads();
  const int b = bh >> 4, h = bh & 15;
  long obase = ((long)(b * T + q0) << 11) + h * 128;
#pragma unroll
  for (int j = 0; j < 8; ++j) {
    int u = j * 512 + tid;
    int r = u >> 4, c = u & 15;
    *(short8*)(Out + obase + ((long)r << 11) + c * 8) =
        *(const short8*)(lds + r * 128 + c * 8);
  }
}

extern "C" void kernel_launch(void* const* d_in, const int* in_sizes, int n_in,
                              void* d_out, int out_size, void* d_ws, size_t ws_size,
                              hipStream_t stream) {
  const float* x    = (const float*)d_in[0];
  const float* pos  = (const float*)d_in[1];
  const float* wq_w = (const float*)d_in[2];
  const float* wq_b = (const float*)d_in[3];
  const float* wk_w = (const float*)d_in[4];
  const float* wk_b = (const float*)d_in[5];
  const float* wv_w = (const float*)d_in[6];
  const float* wv_b = (const float*)d_in[7];
  const float* wo_w = (const float*)d_in[8];
  const float* wo_b = (const float*)d_in[9];

  unsigned short* xb  = (unsigned short*)d_ws;
  unsigned short* wqb = xb  + (1u << 24);
  unsigned short* wkb = wqb + (1u << 22);
  unsigned short* wvb = wkb + (1u << 22);
  unsigned short* wob = wvb + (1u << 22);
  unsigned short* qb  = wob + (1u << 22);
  unsigned short* kb  = qb  + (1u << 24);
  unsigned short* vtb = kb  + (1u << 24);
  unsigned short* ab  = vtb + (1u << 24);   // attention output, bf16 [8192][2048]
  float2* cst = (float2*)ab;                // cos/sin table aliases ab (dead until flash)

  cast_kernel<<<16384, 256, 0, stream>>>((const float4*)x, (ushortx4*)xb);
  cast_kernel<<<4096, 256, 0, stream>>>((const float4*)wq_w, (ushortx4*)wqb);
  cast_kernel<<<4096, 256, 0, stream>>>((const float4*)wk_w, (ushortx4*)wkb);
  cast_kernel<<<4096, 256, 0, stream>>>((const float4*)wv_w, (ushortx4*)wvb);
  cast_kernel<<<4096, 256, 0, stream>>>((const float4*)wo_w, (ushortx4*)wob);
  cs_table_kernel<<<512, 256, 0, stream>>>(pos, cst);

  qkv_gemm<<<3072, 256, 0, stream>>>(xb, wqb, wkb, wvb, wq_b, wk_b, wv_b,
                                     qb, kb, vtb, cst);
  flash_kernel<<<512, 512, 0, stream>>>(qb, kb, vtb, ab);
  gemm_wo<<<1024, 256, 0, stream>>>(ab, wob, wo_b, (float*)d_out);
}

// Round 8
// 675.877 us; speedup vs baseline: 1.0658x; 1.0658x over previous
//
#include <hip/hip_runtime.h>

// Attention (B=4, T=2048, dim=2048, H=16, hd=128) on gfx950.
// Pipeline: cast->bf16 | cos/sin table | fused QKV gemm (RoPE in epilogue) |
//           flash attention | out gemm.
// R10: merge of verified-best components. GEMMs = R7's 256x256/BK=32 triple-buffered
//      counted-vmcnt structure (R9's m97-class replica measured ~50us slower aggregate).
//      Flash = R5-verified softmax (R7's defer-rescale regressed). No new mechanisms.
// Workspace layout (192 MiB):
//   xb[2^24] wqb wkb wvb wob[2^22 each] qb[2^24] kb[2^24] vtb[2^24] ab[2^24]  (bf16)
//   cs-table (1 MiB float2[2048][64]) aliases ab (dead until flash writes it).

using floatx4  = __attribute__((ext_vector_type(4))) float;
using short8   = __attribute__((ext_vector_type(8))) short;
using ushortx4 = __attribute__((ext_vector_type(4))) unsigned short;

#define DEVFN static __device__ __forceinline__

DEVFN unsigned short f2bf(float f) {          // RNE float->bf16
  unsigned u = __builtin_bit_cast(unsigned, f);
  u += 0x7fffu + ((u >> 16) & 1u);
  return (unsigned short)(u >> 16);
}
DEVFN float bf2f(unsigned short h) {
  return __builtin_bit_cast(float, ((unsigned)h) << 16);
}

DEVFN void async_cp16(const unsigned short* g, unsigned short* l) {
  __builtin_amdgcn_global_load_lds(
      (const __attribute__((address_space(1))) void*)g,
      (__attribute__((address_space(3))) void*)l,
      16, 0, 0);
}

// ---------------- cast fp32 -> bf16 (vectorized) ----------------
__global__ __launch_bounds__(256) void cast_kernel(const float4* __restrict__ in,
                                                   ushortx4* __restrict__ out) {
  long u = (long)blockIdx.x * 256 + threadIdx.x;
  float4 v = in[u];
  out[u] = (ushortx4){f2bf(v.x), f2bf(v.y), f2bf(v.z), f2bf(v.w)};
}

// ---------------- cos/sin table: cst[t][j] = {cos,sin}(pos[t]*freq_j) ----------------
__global__ __launch_bounds__(256) void cs_table_kernel(const float* __restrict__ pos,
                                                       float2* __restrict__ cst) {
  int idx = blockIdx.x * 256 + threadIdx.x;   // 2048*64 entries, grid 512
  int t = idx >> 6, j = idx & 63;
  float ang = pos[t] * exp2f(-0.20762051f * (float)j);  // 10000^(-j/64)
  cst[idx] = make_float2(cosf(ang), sinf(ang));
}

// ---------------- fused QKV GEMM: C[m,n] = sum_k A[m,k]*W[n,k] + bias[n] ------------
// M=8192 N=2048 K=2048 x3 weight matrices in one 768-block launch (g = bid>>8).
// 256x256 tile, BK=32, 8 waves, triple-buffered LDS, counted vmcnt, raw s_barrier.
// g<2 (Q,K): bf16 out [B,H,T,hd] with RoPE applied in epilogue.
// g==2 (V): bf16 out [B,H,hd,T] (transposed). All stores LDS-restaged, 16B coalesced.
__global__ __launch_bounds__(512, 2) void qkv_gemm(
    const unsigned short* __restrict__ A,
    const unsigned short* __restrict__ Wq, const unsigned short* __restrict__ Wk,
    const unsigned short* __restrict__ Wv,
    const float* __restrict__ bq, const float* __restrict__ bk,
    const float* __restrict__ bv,
    unsigned short* __restrict__ Oq, unsigned short* __restrict__ Ok,
    unsigned short* __restrict__ Ov,
    const float2* __restrict__ cst) {
  constexpr int K = 2048;
  constexpr int NT = 64;
  __shared__ __align__(16) unsigned short lds[49152];   // 96 KiB: 3 bufs x 16384
  const int tid = threadIdx.x;
  const int wave = tid >> 6, lane = tid & 63;
  const int ln15 = lane & 15, quad = lane >> 4;
  const int wm = wave >> 2, wn = wave & 3;
  const int bid = blockIdx.x;
  const int g = bid >> 8;                        // 0:q 1:k 2:v
  const int b2 = bid & 255;
  const unsigned short* Bw = (g == 0) ? Wq : (g == 1) ? Wk : Wv;
  const float* bias = (g == 0) ? bq : (g == 1) ? bk : bv;
  unsigned short* Cout = (g == 0) ? Oq : (g == 1) ? Ok : Ov;
  const int xcd = b2 & 7, sl = b2 >> 3;
  const int m0 = (xcd * 4 + (sl & 3)) * 256;
  const int n0 = (sl >> 2) * 256;

  // per-thread stage sources (inverse-swizzled global addr, linear LDS dst)
  const unsigned short *srcA0, *srcA1, *srcB0, *srcB1;
  {
    int u = tid;
    int L = u >> 3, cc = (u & 7) ^ (L & 7);
    int row = L * 2 + (cc >> 2), col = (cc & 3) * 8;
    srcA0 = A + (long)(m0 + row) * K + col;
    srcB0 = Bw + (long)(n0 + row) * K + col;
  }
  {
    int u = tid + 512;
    int L = u >> 3, cc = (u & 7) ^ (L & 7);
    int row = L * 2 + (cc >> 2), col = (cc & 3) * 8;
    srcA1 = A + (long)(m0 + row) * K + col;
    srcB1 = Bw + (long)(n0 + row) * K + col;
  }
  const int sdst = wave * 512;

#define STAGE_G(t, bufp)                                                \
  do {                                                                  \
    async_cp16(srcA0 + (long)(t) * 32, (bufp) + sdst);                  \
    async_cp16(srcA1 + (long)(t) * 32, (bufp) + 4096 + sdst);           \
    async_cp16(srcB0 + (long)(t) * 32, (bufp) + 8192 + sdst);           \
    async_cp16(srcB1 + (long)(t) * 32, (bufp) + 12288 + sdst);          \
  } while (0)

  int offA[8], offB[4];
#pragma unroll
  for (int mi = 0; mi < 8; ++mi) {
    int row = wm * 128 + mi * 16 + ln15;
    int line = row >> 1, cc = (row & 1) * 4 + quad;
    offA[mi] = line * 64 + (cc ^ (line & 7)) * 8;
  }
#pragma unroll
  for (int nj = 0; nj < 4; ++nj) {
    int row = wn * 64 + nj * 16 + ln15;
    int line = row >> 1, cc = (row & 1) * 4 + quad;
    offB[nj] = 8192 + line * 64 + (cc ^ (line & 7)) * 8;
  }

  floatx4 acc[8][4];
#pragma unroll
  for (int i = 0; i < 8; ++i)
#pragma unroll
    for (int j = 0; j < 4; ++j) acc[i][j] = (floatx4){0.f, 0.f, 0.f, 0.f};

  unsigned short* const bA0 = lds;
  unsigned short* const bA1 = lds + 16384;
  unsigned short* const bA2 = lds + 32768;

  STAGE_G(0, bA0);
  STAGE_G(1, bA1);
  asm volatile("s_waitcnt vmcnt(4)" ::: "memory");
  __builtin_amdgcn_s_barrier();

  int cb = 0;
  for (int t = 0; t < NT; ++t) {
    unsigned short* cur = (cb == 0) ? bA0 : ((cb == 1) ? bA1 : bA2);
    if (t < NT - 2) {
      int nb = cb ? cb - 1 : 2;
      unsigned short* nxt = (nb == 0) ? bA0 : ((nb == 1) ? bA1 : bA2);
      STAGE_G(t + 2, nxt);
    }
    short8 af[8], bf4[4];
#pragma unroll
    for (int mi = 0; mi < 8; ++mi) af[mi] = *(const short8*)(cur + offA[mi]);
#pragma unroll
    for (int nj = 0; nj < 4; ++nj) bf4[nj] = *(const short8*)(cur + offB[nj]);
    __builtin_amdgcn_s_setprio(1);
#pragma unroll
    for (int mi = 0; mi < 8; ++mi)
#pragma unroll
      for (int nj = 0; nj < 4; ++nj)
        acc[mi][nj] = __builtin_amdgcn_mfma_f32_16x16x32_bf16(af[mi], bf4[nj],
                                                              acc[mi][nj], 0, 0, 0);
    __builtin_amdgcn_s_setprio(0);
    if (t < NT - 2) {
      asm volatile("s_waitcnt vmcnt(4)" ::: "memory");
    } else if (t == NT - 2) {
      asm volatile("s_waitcnt vmcnt(0)" ::: "memory");
    }
    __builtin_amdgcn_s_barrier();
    cb = (cb == 2) ? 0 : cb + 1;
  }
#undef STAGE_G

  const int b_ = m0 >> 11;
  const int t0m = m0 & 2047;
  const int h0 = n0 >> 7;

  if (g == 2) {
    // V: out [b][h][d][t]. LDS [256 n][128 tl], chunk c=tl>>3, phys = c ^ (n&15)
#pragma unroll
    for (int rnd = 0; rnd < 2; ++rnd) {
      __syncthreads();
      if (wm == rnd) {
#pragma unroll
        for (int nj = 0; nj < 4; ++nj) {
          int nloc = wn * 64 + nj * 16 + ln15;
          float bv = bias[n0 + nloc];
#pragma unroll
          for (int mi = 0; mi < 8; ++mi)
#pragma unroll
            for (int r = 0; r < 4; ++r) {
              int tl = mi * 16 + quad * 4 + r;
              int phys = (tl >> 3) ^ (nloc & 15);
              lds[nloc * 128 + phys * 8 + (tl & 7)] = f2bf(acc[mi][nj][r] + bv);
            }
        }
      }
      __syncthreads();
#pragma unroll
      for (int j = 0; j < 8; ++j) {
        int u = j * 512 + tid;
        int nloc = u >> 4, c = u & 15;
        int phys = c ^ (nloc & 15);
        int h = h0 + (nloc >> 7), d = nloc & 127;
        *(short8*)(Cout +
                   ((((long)(b_ * 16 + h)) << 7) + d) * 2048 + t0m + rnd * 128 + c * 8) =
            *(const short8*)(lds + nloc * 128 + phys * 8);
      }
    }
  } else {
    // Q/K: out [b][h][t][d] with RoPE. LDS [128 tl][256 n], chunk c=n>>3, phys=c^(tl&15)
#pragma unroll
    for (int rnd = 0; rnd < 2; ++rnd) {
      __syncthreads();
      if (wm == rnd) {
#pragma unroll
        for (int nj = 0; nj < 4; ++nj) {
          int nloc = wn * 64 + nj * 16 + ln15;
          float bv = bias[n0 + nloc];
#pragma unroll
          for (int mi = 0; mi < 8; ++mi)
#pragma unroll
            for (int r = 0; r < 4; ++r) {
              int tl = mi * 16 + quad * 4 + r;
              int phys = (nloc >> 3) ^ (tl & 15);
              lds[tl * 256 + phys * 8 + (nloc & 7)] = f2bf(acc[mi][nj][r] + bv);
            }
        }
      }
      __syncthreads();
#pragma unroll
      for (int j = 0; j < 8; ++j) {
        int u = j * 512 + tid;
        int tl = u >> 5, c = u & 31;
        int phys = c ^ (tl & 15);
        int hh = h0 + (c >> 4);
        int tt = t0m + rnd * 128 + tl;
        int cl = c & 15;                            // d0 = cl*8
        int cp = (cl < 8) ? c + 8 : c - 8;          // partner chunk (d +/- 64)
        int physp = cp ^ (tl & 15);
        short8 s8 = *(const short8*)(lds + tl * 256 + phys * 8);
        short8 p8 = *(const short8*)(lds + tl * 256 + physp * 8);
        const float2* ct = cst + tt * 64 + (cl & 7) * 8;
        short8 o8;
#pragma unroll
        for (int e = 0; e < 8; ++e) {
          float2 cs = ct[e];
          float x = bf2f((unsigned short)s8[e]);
          float y = bf2f((unsigned short)p8[e]);
          float v = (cl < 8) ? (x * cs.x - y * cs.y) : (x * cs.x + y * cs.y);
          o8[e] = (short)f2bf(v);
        }
        *(short8*)(Cout + ((((long)(b_ * 16 + hh)) << 11) + tt) * 128 + cl * 8) = o8;
      }
    }
  }
}

// ---------------- output GEMM (wo): fp32 out [M,N] ----------------
__global__ __launch_bounds__(512, 2) void gemm_wo(const unsigned short* __restrict__ A,
                                                  const unsigned short* __restrict__ Bw,
                                                  const float* __restrict__ bias,
                                                  float* __restrict__ Cout) {
  constexpr int K = 2048;
  constexpr int NT = 64;
  __shared__ __align__(16) unsigned short lds[49152];
  const int tid = threadIdx.x;
  const int wave = tid >> 6, lane = tid & 63;
  const int ln15 = lane & 15, quad = lane >> 4;
  const int wm = wave >> 2, wn = wave & 3;
  const int bid = blockIdx.x;
  const int xcd = bid & 7, sl = bid >> 3;
  const int m0 = (xcd * 4 + (sl & 3)) * 256;
  const int n0 = (sl >> 2) * 256;

  const unsigned short *srcA0, *srcA1, *srcB0, *srcB1;
  {
    int u = tid;
    int L = u >> 3, cc = (u & 7) ^ (L & 7);
    int row = L * 2 + (cc >> 2), col = (cc & 3) * 8;
    srcA0 = A + (long)(m0 + row) * K + col;
    srcB0 = Bw + (long)(n0 + row) * K + col;
  }
  {
    int u = tid + 512;
    int L = u >> 3, cc = (u & 7) ^ (L & 7);
    int row = L * 2 + (cc >> 2), col = (cc & 3) * 8;
    srcA1 = A + (long)(m0 + row) * K + col;
    srcB1 = Bw + (long)(n0 + row) * K + col;
  }
  const int sdst = wave * 512;

#define STAGE_G(t, bufp)                                                \
  do {                                                                  \
    async_cp16(srcA0 + (long)(t) * 32, (bufp) + sdst);                  \
    async_cp16(srcA1 + (long)(t) * 32, (bufp) + 4096 + sdst);           \
    async_cp16(srcB0 + (long)(t) * 32, (bufp) + 8192 + sdst);           \
    async_cp16(srcB1 + (long)(t) * 32, (bufp) + 12288 + sdst);          \
  } while (0)

  int offA[8], offB[4];
#pragma unroll
  for (int mi = 0; mi < 8; ++mi) {
    int row = wm * 128 + mi * 16 + ln15;
    int line = row >> 1, cc = (row & 1) * 4 + quad;
    offA[mi] = line * 64 + (cc ^ (line & 7)) * 8;
  }
#pragma unroll
  for (int nj = 0; nj < 4; ++nj) {
    int row = wn * 64 + nj * 16 + ln15;
    int line = row >> 1, cc = (row & 1) * 4 + quad;
    offB[nj] = 8192 + line * 64 + (cc ^ (line & 7)) * 8;
  }

  floatx4 acc[8][4];
#pragma unroll
  for (int i = 0; i < 8; ++i)
#pragma unroll
    for (int j = 0; j < 4; ++j) acc[i][j] = (floatx4){0.f, 0.f, 0.f, 0.f};

  unsigned short* const bA0 = lds;
  unsigned short* const bA1 = lds + 16384;
  unsigned short* const bA2 = lds + 32768;

  STAGE_G(0, bA0);
  STAGE_G(1, bA1);
  asm volatile("s_waitcnt vmcnt(4)" ::: "memory");
  __builtin_amdgcn_s_barrier();

  int cb = 0;
  for (int t = 0; t < NT; ++t) {
    unsigned short* cur = (cb == 0) ? bA0 : ((cb == 1) ? bA1 : bA2);
    if (t < NT - 2) {
      int nb = cb ? cb - 1 : 2;
      unsigned short* nxt = (nb == 0) ? bA0 : ((nb == 1) ? bA1 : bA2);
      STAGE_G(t + 2, nxt);
    }
    short8 af[8], bf4[4];
#pragma unroll
    for (int mi = 0; mi < 8; ++mi) af[mi] = *(const short8*)(cur + offA[mi]);
#pragma unroll
    for (int nj = 0; nj < 4; ++nj) bf4[nj] = *(const short8*)(cur + offB[nj]);
    __builtin_amdgcn_s_setprio(1);
#pragma unroll
    for (int mi = 0; mi < 8; ++mi)
#pragma unroll
      for (int nj = 0; nj < 4; ++nj)
        acc[mi][nj] = __builtin_amdgcn_mfma_f32_16x16x32_bf16(af[mi], bf4[nj],
                                                              acc[mi][nj], 0, 0, 0);
    __builtin_amdgcn_s_setprio(0);
    if (t < NT - 2) {
      asm volatile("s_waitcnt vmcnt(4)" ::: "memory");
    } else if (t == NT - 2) {
      asm volatile("s_waitcnt vmcnt(0)" ::: "memory");
    }
    __builtin_amdgcn_s_barrier();
    cb = (cb == 2) ? 0 : cb + 1;
  }
#undef STAGE_G

  // fp32 epilogue: LDS f32 [64 tl][256 n], chunk c=n>>2 (64), phys = c ^ (tl&15)
  float* lf = (float*)lds;
#pragma unroll
  for (int rnd = 0; rnd < 4; ++rnd) {
    __syncthreads();
    if (wm == (rnd >> 1)) {
#pragma unroll
      for (int nj = 0; nj < 4; ++nj) {
        int nloc = wn * 64 + nj * 16 + ln15;
        float bv = bias[n0 + nloc];
#pragma unroll
        for (int mh = 0; mh < 4; ++mh) {
          int mi = (rnd & 1) * 4 + mh;
#pragma unroll
          for (int r = 0; r < 4; ++r) {
            int tl = mh * 16 + quad * 4 + r;
            int phys = (nloc >> 2) ^ (tl & 15);
            lf[tl * 256 + phys * 4 + (nloc & 3)] = acc[mi][nj][r] + bv;
          }
        }
      }
    }
    __syncthreads();
#pragma unroll
    for (int j = 0; j < 8; ++j) {
      int u = j * 512 + tid;
      int tl = u >> 6, c = u & 63;
      int phys = c ^ (tl & 15);
      int m = m0 + rnd * 64 + tl;
      *(floatx4*)(Cout + (long)m * 2048 + n0 + c * 4) =
          *(const floatx4*)(lf + tl * 256 + phys * 4);
    }
  }
}

// ---------------- flash attention (R5-verified) ----------------
// Grid 512, 512 threads (8 waves x 32 q-rows). KVBLK=64, K/V gload_lds double-buffered,
// wave-private P, LDS-staged coalesced output.
__global__ __launch_bounds__(512, 2) void flash_kernel(
    const unsigned short* __restrict__ Q,    // [64][2048][128]
    const unsigned short* __restrict__ Kmat, // [64][2048][128]
    const unsigned short* __restrict__ Vt,   // [64][128][2048]
    unsigned short* __restrict__ Out) {      // [4][2048][2048]
  constexpr int T = 2048;
  constexpr float SCALE = 0.08838834764831845f;  // 1/sqrt(128)
  __shared__ __align__(16) unsigned short lds[49152];  // 96 KiB

  const int tid = threadIdx.x;
  const int wave = tid >> 6, lane = tid & 63;
  const int ln15 = lane & 15, quad = lane >> 4;
  const int l7 = ln15 & 7;
  const int bid = blockIdx.x;
  const int xcd = bid & 7, sl = bid >> 3;
  const int bh = xcd * 8 + (sl >> 3);
  const int q0 = (sl & 7) * 256;

  const unsigned short* Qb = Q + (long)bh * T * 128;
  const unsigned short* Kb = Kmat + (long)bh * T * 128;
  const unsigned short* Vb = Vt + (long)bh * 128 * T;
  unsigned short* pw = lds + 32768 + wave * 2048;

  short8 qf[2][4];
#pragma unroll
  for (int mi = 0; mi < 2; ++mi)
#pragma unroll
    for (int ks = 0; ks < 4; ++ks)
      qf[mi][ks] = *(const short8*)(Qb + (long)(q0 + wave * 32 + mi * 16 + ln15) * 128 +
                                    ks * 32 + quad * 8);

#define STAGE_KV(t, kdst, vdst)                                                  \
  do {                                                                           \
    _Pragma("unroll") for (int j = 0; j < 2; ++j) {                              \
      int u = j * 512 + tid;                                                     \
      int row = u >> 4;                                                          \
      int c = (u & 15) ^ (row & 15);                                             \
      async_cp16(Kb + (long)((t) * 64 + row) * 128 + c * 8,                      \
                 (kdst) + (j * 512 + wave * 64) * 8);                            \
    }                                                                            \
    _Pragma("unroll") for (int j = 0; j < 2; ++j) {                              \
      int u = j * 512 + tid;                                                     \
      int row = u >> 3;                                                          \
      int c = (u & 7) ^ (row & 7);                                               \
      async_cp16(Vb + (long)row * T + (t) * 64 + c * 8,                          \
                 (vdst) + (j * 512 + wave * 64) * 8);                            \
    }                                                                            \
  } while (0)

  STAGE_KV(0, lds, lds + 16384);
  asm volatile("s_waitcnt vmcnt(0)" ::: "memory");
  __syncthreads();

  floatx4 oacc[2][8];
#pragma unroll
  for (int mi = 0; mi < 2; ++mi)
#pragma unroll
    for (int nj = 0; nj < 8; ++nj) oacc[mi][nj] = (floatx4){0.f, 0.f, 0.f, 0.f};
  float mst[2][4], lsp[2][4];
#pragma unroll
  for (int mi = 0; mi < 2; ++mi)
#pragma unroll
    for (int r = 0; r < 4; ++r) { mst[mi][r] = -1e30f; lsp[mi][r] = 0.f; }

  for (int t = 0; t < 32; ++t) {
    unsigned short* kc = lds + (t & 1) * 8192;
    unsigned short* vc = lds + 16384 + (t & 1) * 8192;
    if (t < 31) {
      unsigned short* kn = lds + ((t + 1) & 1) * 8192;
      unsigned short* vn = lds + 16384 + ((t + 1) & 1) * 8192;
      STAGE_KV(t + 1, kn, vn);
    }

    floatx4 sacc[2][4];
#pragma unroll
    for (int mi = 0; mi < 2; ++mi)
#pragma unroll
      for (int ni = 0; ni < 4; ++ni) sacc[mi][ni] = (floatx4){0.f, 0.f, 0.f, 0.f};
#pragma unroll
    for (int ks = 0; ks < 4; ++ks) {
      short8 bfr[4];
#pragma unroll
      for (int ni = 0; ni < 4; ++ni) {
        int row = ni * 16 + ln15;
        int phys = (ks * 4 + quad) ^ ln15;
        bfr[ni] = *(const short8*)(kc + row * 128 + phys * 8);
      }
      __builtin_amdgcn_s_setprio(1);
#pragma unroll
      for (int mi = 0; mi < 2; ++mi)
#pragma unroll
        for (int ni = 0; ni < 4; ++ni)
          sacc[mi][ni] = __builtin_amdgcn_mfma_f32_16x16x32_bf16(qf[mi][ks], bfr[ni],
                                                                 sacc[mi][ni], 0, 0, 0);
      __builtin_amdgcn_s_setprio(0);
    }

    // online softmax (R5 form, unconditional rescale)
#pragma unroll
    for (int mi = 0; mi < 2; ++mi)
#pragma unroll
      for (int r = 0; r < 4; ++r) {
        float mx = fmaxf(fmaxf(sacc[mi][0][r], sacc[mi][1][r]),
                         fmaxf(sacc[mi][2][r], sacc[mi][3][r]));
#pragma unroll
        for (int off = 1; off < 16; off <<= 1) mx = fmaxf(mx, __shfl_xor(mx, off, 16));
        mx *= SCALE;
        float mold = mst[mi][r];
        float mnew = fmaxf(mold, mx);
        float alpha = __expf(mold - mnew);
        float rs = 0.f;
#pragma unroll
        for (int ni = 0; ni < 4; ++ni) {
          float p = __expf(sacc[mi][ni][r] * SCALE - mnew);
          sacc[mi][ni][r] = p;
          rs += p;
        }
        mst[mi][r] = mnew;
        lsp[mi][r] = lsp[mi][r] * alpha + rs;
#pragma unroll
        for (int nj = 0; nj < 8; ++nj) oacc[mi][nj][r] *= alpha;
      }

#pragma unroll
    for (int mi = 0; mi < 2; ++mi)
#pragma unroll
      for (int ni = 0; ni < 4; ++ni) {
        int cc = ni * 2 + (ln15 >> 3);
#pragma unroll
        for (int r = 0; r < 4; ++r) {
          int m = mi * 16 + quad * 4 + r;
          pw[m * 64 + (cc ^ (m & 7)) * 8 + l7] = f2bf(sacc[mi][ni][r]);
        }
      }

#pragma unroll
    for (int ks = 0; ks < 2; ++ks) {
      short8 af[2], bv[8];
#pragma unroll
      for (int mi = 0; mi < 2; ++mi) {
        int phys = (ks * 4 + quad) ^ l7;
        af[mi] = *(const short8*)(pw + (mi * 16 + ln15) * 64 + phys * 8);
      }
#pragma unroll
      for (int nj = 0; nj < 8; ++nj) {
        int row = nj * 16 + ln15;
        int phys = (ks * 4 + quad) ^ (row & 7);
        bv[nj] = *(const short8*)(vc + row * 64 + phys * 8);
      }
      __builtin_amdgcn_s_setprio(1);
#pragma unroll
      for (int mi = 0; mi < 2; ++mi)
#pragma unroll
        for (int nj = 0; nj < 8; ++nj)
          oacc[mi][nj] = __builtin_amdgcn_mfma_f32_16x16x32_bf16(af[mi], bv[nj],
                                                                 oacc[mi][nj], 0, 0, 0);
      __builtin_amdgcn_s_setprio(0);
    }

    asm volatile("s_waitcnt vmcnt(0)" ::: "memory");
    __syncthreads();
  }
#undef STAGE_KV

  float rinv[2][4];
#pragma unroll
  for (int mi = 0; mi < 2; ++mi)
#pragma unroll
    for (int r = 0; r < 4; ++r) {
      float l = lsp[mi][r];
#pragma unroll
      for (int off = 1; off < 16; off <<= 1) l += __shfl_xor(l, off, 16);
      rinv[mi][r] = 1.f / l;
    }
#pragma unroll
  for (int mi = 0; mi < 2; ++mi)
#pragma unroll
    for (int nj = 0; nj < 8; ++nj)
#pragma unroll
      for (int r = 0; r < 4; ++r)
        lds[(wave * 32 + mi * 16 + quad * 4 + r) * 128 + nj * 16 + ln15] =
            f2bf(oacc[mi][nj][r] * rinv[mi][r]);
  __syncthreads();
  const int b = bh >> 4, h = bh & 15;
  long obase = ((long)(b * T + q0) << 11) + h * 128;
#pragma unroll
  for (int j = 0; j < 8; ++j) {
    int u = j * 512 + tid;
    int r = u >> 4, c = u & 15;
    *(short8*)(Out + obase + ((long)r << 11) + c * 8) =
        *(const short8*)(lds + r * 128 + c * 8);
  }
}

extern "C" void kernel_launch(void* const* d_in, const int* in_sizes, int n_in,
                              void* d_out, int out_size, void* d_ws, size_t ws_size,
                              hipStream_t stream) {
  const float* x    = (const float*)d_in[0];
  const float* pos  = (const float*)d_in[1];
  const float* wq_w = (const float*)d_in[2];
  const float* wq_b = (const float*)d_in[3];
  const float* wk_w = (const float*)d_in[4];
  const float* wk_b = (const float*)d_in[5];
  const float* wv_w = (const float*)d_in[6];
  const float* wv_b = (const float*)d_in[7];
  const float* wo_w = (const float*)d_in[8];
  const float* wo_b = (const float*)d_in[9];

  unsigned short* xb  = (unsigned short*)d_ws;
  unsigned short* wqb = xb  + (1u << 24);
  unsigned short* wkb = wqb + (1u << 22);
  unsigned short* wvb = wkb + (1u << 22);
  unsigned short* wob = wvb + (1u << 22);
  unsigned short* qb  = wob + (1u << 22);
  unsigned short* kb  = qb  + (1u << 24);
  unsigned short* vtb = kb  + (1u << 24);
  unsigned short* ab  = vtb + (1u << 24);   // attention output, bf16 [8192][2048]
  float2* cst = (float2*)ab;                // cos/sin table aliases ab (dead until flash)

  cast_kernel<<<16384, 256, 0, stream>>>((const float4*)x, (ushortx4*)xb);
  cast_kernel<<<4096, 256, 0, stream>>>((const float4*)wq_w, (ushortx4*)wqb);
  cast_kernel<<<4096, 256, 0, stream>>>((const float4*)wk_w, (ushortx4*)wkb);
  cast_kernel<<<4096, 256, 0, stream>>>((const float4*)wv_w, (ushortx4*)wvb);
  cast_kernel<<<4096, 256, 0, stream>>>((const float4*)wo_w, (ushortx4*)wob);
  cs_table_kernel<<<512, 256, 0, stream>>>(pos, cst);

  qkv_gemm<<<768, 512, 0, stream>>>(xb, wqb, wkb, wvb, wq_b, wk_b, wv_b,
                                    qb, kb, vtb, cst);
  flash_kernel<<<512, 512, 0, stream>>>(qb, kb, vtb, ab);
  gemm_wo<<<256, 512, 0, stream>>>(ab, wob, wo_b, (float*)d_out);
}